// Round 1
// baseline (749.313 us; speedup 1.0000x reference)
//
#include <hip/hip_runtime.h>
#include <hip/hip_bf16.h>
#include <math.h>

// Problem constants
#define SEQ 2048
#define DIM 4096
#define NH 32
#define NKV 8
#define HD 128
#define KVD 1024              // NKV*HD
#define SCALE 0.08838834764831845f
#define NEGBIG -1000000000.0f

typedef __bf16 bf16;
typedef __attribute__((ext_vector_type(2))) __bf16 bf16x2;
typedef __attribute__((ext_vector_type(4))) __bf16 bf16x4;
typedef __attribute__((ext_vector_type(8))) __bf16 bf16x8;
typedef __attribute__((ext_vector_type(4))) float f32x4;

// ---------------------------------------------------------------------------
// async global->LDS 16B copy (wave-uniform LDS base + lane*16 semantics)
__device__ __forceinline__ void async_g2l16(const bf16* g, bf16* l) {
  __builtin_amdgcn_global_load_lds(
      (const __attribute__((address_space(1))) void*)g,
      (__attribute__((address_space(3))) void*)l,
      16, 0, 0);
}

// ---------------------------------------------------------------------------
// fp32 -> bf16 cast, float4 vectorized
__global__ void cast_bf16_kernel(const float* __restrict__ in,
                                 bf16* __restrict__ out, int n4) {
  int i = blockIdx.x * 256 + threadIdx.x;
  if (i >= n4) return;
  float4 v = ((const float4*)in)[i];
  bf16x4 o;
  o[0] = (bf16)v.x; o[1] = (bf16)v.y; o[2] = (bf16)v.z; o[3] = (bf16)v.w;
  ((bf16x4*)out)[i] = o;
}

// ---------------------------------------------------------------------------
// m97-style B^T GEMM body: C[M x N](fp32) = A[M x K](bf16,row-major) * B^T
// where B is [N x K] bf16 row-major. 128x128 tile, BK=32, 256 threads.
__device__ __forceinline__ void gemm_bt_body(
    const bf16* __restrict__ A, int lda,
    const bf16* __restrict__ B, int ldb,
    float* __restrict__ C, int ldc,
    int K, int mBase)
{
  __shared__ __align__(16) bf16 As[128 * 32];
  __shared__ __align__(16) bf16 Bs[128 * 32];

  const int tid  = threadIdx.x;
  const int lane = tid & 63;
  const int w    = tid >> 6;
  const int l15  = lane & 15;
  const int quad = lane >> 4;
  const int wr   = (w >> 1) * 64;
  const int wc   = (w & 1) * 64;

  // staging: each wave does 2 chunks of 16 rows for A and B.
  const int srow = lane >> 2;          // 0..15 within chunk
  const int skp  = (lane & 3) * 8;     // 0,8,16,24 elements within 32-wide k
  const bf16* gA0 = A + (size_t)(mBase + w * 16 + srow) * lda + skp;
  const bf16* gA1 = gA0 + (size_t)64 * lda;
  const bf16* gB0 = B + (size_t)(w * 16 + srow) * ldb + skp;
  const bf16* gB1 = gB0 + (size_t)64 * ldb;
  bf16* lA0 = As + w * 512;            // wave-uniform LDS bases
  bf16* lA1 = As + (w + 4) * 512;
  bf16* lB0 = Bs + w * 512;
  bf16* lB1 = Bs + (w + 4) * 512;

  const f32x4 vzero = {0.f, 0.f, 0.f, 0.f};
  f32x4 acc[4][4];
#pragma unroll
  for (int mi = 0; mi < 4; ++mi)
#pragma unroll
    for (int ni = 0; ni < 4; ++ni) acc[mi][ni] = vzero;

  for (int k0 = 0; k0 < K; k0 += 32) {
    __syncthreads();                   // previous tile's ds_reads done
    async_g2l16(gA0 + k0, lA0);
    async_g2l16(gA1 + k0, lA1);
    async_g2l16(gB0 + k0, lB0);
    async_g2l16(gB1 + k0, lB1);
    __syncthreads();                   // vmcnt(0) drained before barrier

    bf16x8 a[4], b[4];
#pragma unroll
    for (int mi = 0; mi < 4; ++mi)
      a[mi] = *(const bf16x8*)(As + (wr + mi * 16 + l15) * 32 + quad * 8);
#pragma unroll
    for (int ni = 0; ni < 4; ++ni)
      b[ni] = *(const bf16x8*)(Bs + (wc + ni * 16 + l15) * 32 + quad * 8);
#pragma unroll
    for (int mi = 0; mi < 4; ++mi)
#pragma unroll
      for (int ni = 0; ni < 4; ++ni)
        acc[mi][ni] = __builtin_amdgcn_mfma_f32_16x16x32_bf16(
            a[mi], b[ni], acc[mi][ni], 0, 0, 0);
  }

  // epilogue: C/D layout col=lane&15, row=quad*4+r (m89-verified)
#pragma unroll
  for (int mi = 0; mi < 4; ++mi) {
    int row = mBase + wr + mi * 16 + quad * 4;
#pragma unroll
    for (int ni = 0; ni < 4; ++ni) {
      int col = wc + ni * 16 + l15;
#pragma unroll
      for (int r = 0; r < 4; ++r)
        C[(size_t)(row + r) * ldc + col] = acc[mi][ni][r];
    }
  }
}

// QKV projection: x(2048x4096) @ {wq,wk,wv}^T -> Qf, Kf, Vf (fp32)
__global__ __launch_bounds__(256, 2) void qkv_gemm_kernel(
    const bf16* __restrict__ xb, const bf16* __restrict__ wqb,
    const bf16* __restrict__ wkb, const bf16* __restrict__ wvb,
    float* __restrict__ Qf, float* __restrict__ Kf, float* __restrict__ Vf)
{
  int nb = blockIdx.x;                 // 0..47: 32 Q blocks, 8 K, 8 V
  const bf16* B; float* C; int ldc;
  if (nb < 32)      { B = wqb + (size_t)nb * 128 * DIM;        C = Qf + nb * 128;        ldc = DIM; }
  else if (nb < 40) { int t = nb - 32; B = wkb + (size_t)t * 128 * DIM; C = Kf + t * 128; ldc = KVD; }
  else              { int t = nb - 40; B = wvb + (size_t)t * 128 * DIM; C = Vf + t * 128; ldc = KVD; }
  gemm_bt_body(xb, DIM, B, DIM, C, ldc, DIM, blockIdx.y * 128);
}

// Output projection: attn(2048x4096 bf16) @ wo^T -> out (fp32)
__global__ __launch_bounds__(256, 2) void out_gemm_kernel(
    const bf16* __restrict__ attnb, const bf16* __restrict__ wob,
    float* __restrict__ out)
{
  gemm_bt_body(attnb, DIM, wob + (size_t)blockIdx.x * 128 * DIM, DIM,
               out + blockIdx.x * 128, DIM, DIM, blockIdx.y * 128);
}

// ---------------------------------------------------------------------------
// RoPE (interleaved pairs) + bf16 cast; Q also folds in 1/sqrt(HD).
__global__ void rope_q_kernel(const float* __restrict__ Qf,
                              const float* __restrict__ Cb,
                              const float* __restrict__ Sb,
                              bf16* __restrict__ Qb) {
  int i = blockIdx.x * 256 + threadIdx.x;    // S*NH*64 threads
  int di = i & 63;
  int h  = (i >> 6) & (NH - 1);
  int s  = i >> 11;
  size_t base = (size_t)s * DIM + h * HD + 2 * di;
  float2 t = *(const float2*)(Qf + base);
  float c = Cb[s * 64 + di], sn = Sb[s * 64 + di];
  bf16x2 o;
  o[0] = (bf16)((t.x * c - t.y * sn) * SCALE);
  o[1] = (bf16)((t.x * sn + t.y * c) * SCALE);
  *(bf16x2*)(Qb + base) = o;
}

__global__ void rope_k_kernel(const float* __restrict__ Kf,
                              const float* __restrict__ Cb,
                              const float* __restrict__ Sb,
                              bf16* __restrict__ Kb) {
  int i = blockIdx.x * 256 + threadIdx.x;    // S*NKV*64 threads
  int di = i & 63;
  int h  = (i >> 6) & (NKV - 1);
  int s  = i >> 9;
  size_t base = (size_t)s * KVD + h * HD + 2 * di;
  float2 t = *(const float2*)(Kf + base);
  float c = Cb[s * 64 + di], sn = Sb[s * 64 + di];
  bf16x2 o;
  o[0] = (bf16)(t.x * c - t.y * sn);
  o[1] = (bf16)(t.x * sn + t.y * c);
  *(bf16x2*)(Kb + base) = o;
}

// V transpose+cast: Vf (s, kv*128+d) fp32 -> Vt [kv][d][s] bf16
__global__ void vtrans_kernel(const float* __restrict__ Vf,
                              bf16* __restrict__ Vt) {
  __shared__ float tile[32][33];
  int kv = blockIdx.z;
  int d0 = blockIdx.y * 32, s0 = blockIdx.x * 32;
  int tx = threadIdx.x, ty = threadIdx.y;
  tile[ty][tx] = Vf[(size_t)(s0 + ty) * KVD + kv * HD + d0 + tx];
  __syncthreads();
  Vt[(size_t)kv * HD * SEQ + (size_t)(d0 + ty) * SEQ + s0 + tx] =
      (bf16)tile[tx][ty];
}

// ---------------------------------------------------------------------------
// Flash attention: per (q-tile of 128, head). Q/K/Vt/P tiles in LDS (pad 136).
// Online softmax with m/l in LDS. GQA: head h uses kv head h>>2.
__global__ __launch_bounds__(256, 1) void attn_kernel(
    const bf16* __restrict__ Qb, const bf16* __restrict__ Kb,
    const bf16* __restrict__ Vt, bf16* __restrict__ attnb)
{
  constexpr int LQ = 136;              // padded leading dim (bank-conflict-free frags)
  __shared__ __align__(16) bf16 Qs[128 * LQ];
  __shared__ __align__(16) bf16 Ks[128 * LQ];
  __shared__ __align__(16) bf16 Vs[128 * LQ];   // [hd][key]
  __shared__ __align__(16) bf16 Ps[128 * LQ];
  __shared__ float m_sm[128], l_sm[128], a_sm[128], red[2][128];

  const int qt   = 15 - blockIdx.x;    // big tiles first
  const int h    = blockIdx.y;
  const int kvh  = h >> 2;
  const int tid  = threadIdx.x;
  const int lane = tid & 63;
  const int w    = tid >> 6;
  const int l15  = lane & 15;
  const int quad = lane >> 4;
  const int wr   = (w >> 1) * 64;
  const int wc   = (w & 1) * 64;
  const int qbase = qt * 128;

  // stage Q tile (scaled bf16), 8 x 16B chunks per thread
#pragma unroll
  for (int j = 0; j < 8; ++j) {
    int c = tid + 256 * j;             // 0..2047
    int row = c >> 4, ck = c & 15;
    bf16x8 v = *(const bf16x8*)(Qb + (size_t)(qbase + row) * DIM + h * HD + ck * 8);
    *(bf16x8*)(Qs + row * LQ + ck * 8) = v;
  }
  if (tid < 128) { m_sm[tid] = -1e30f; l_sm[tid] = 0.f; }

  const f32x4 vzero = {0.f, 0.f, 0.f, 0.f};
  f32x4 oacc[4][4];
#pragma unroll
  for (int mi = 0; mi < 4; ++mi)
#pragma unroll
    for (int ni = 0; ni < 4; ++ni) oacc[mi][ni] = vzero;

  __syncthreads();

  for (int kt = 0; kt <= qt; ++kt) {
    const int kbase = kt * 128;
    // load K / Vt tiles into regs (overlaps tail of previous iteration)
    bf16x8 kreg[8], vreg[8];
#pragma unroll
    for (int j = 0; j < 8; ++j) {
      int c = tid + 256 * j;
      int row = c >> 4, ck = c & 15;
      kreg[j] = *(const bf16x8*)(Kb + (size_t)(kbase + row) * KVD + kvh * HD + ck * 8);
      vreg[j] = *(const bf16x8*)(Vt + ((size_t)kvh * HD + row) * SEQ + kbase + ck * 8);
    }
    __syncthreads();                   // prior PV reads of Ks/Vs/Ps complete
#pragma unroll
    for (int j = 0; j < 8; ++j) {
      int c = tid + 256 * j;
      int row = c >> 4, ck = c & 15;
      *(bf16x8*)(Ks + row * LQ + ck * 8) = kreg[j];
      *(bf16x8*)(Vs + row * LQ + ck * 8) = vreg[j];
    }
    __syncthreads();                   // tiles staged

    // S = Q @ K^T  (scale pre-folded into Q)
    f32x4 sacc[4][4];
#pragma unroll
    for (int mi = 0; mi < 4; ++mi)
#pragma unroll
      for (int ni = 0; ni < 4; ++ni) sacc[mi][ni] = vzero;
#pragma unroll
    for (int ks = 0; ks < 4; ++ks) {
      bf16x8 aq[4], bk[4];
#pragma unroll
      for (int mi = 0; mi < 4; ++mi)
        aq[mi] = *(const bf16x8*)(Qs + (wr + mi * 16 + l15) * LQ + ks * 32 + quad * 8);
#pragma unroll
      for (int ni = 0; ni < 4; ++ni)
        bk[ni] = *(const bf16x8*)(Ks + (wc + ni * 16 + l15) * LQ + ks * 32 + quad * 8);
#pragma unroll
      for (int mi = 0; mi < 4; ++mi)
#pragma unroll
        for (int ni = 0; ni < 4; ++ni)
          sacc[mi][ni] = __builtin_amdgcn_mfma_f32_16x16x32_bf16(
              aq[mi], bk[ni], sacc[mi][ni], 0, 0, 0);
    }

    // causal mask (diag tile only) + per-row max partials
    const bool diag = (kt == qt);
#pragma unroll
    for (int mi = 0; mi < 4; ++mi) {
#pragma unroll
      for (int r = 0; r < 4; ++r) {
        int row = wr + mi * 16 + quad * 4 + r;
        float mx = -1e30f;
#pragma unroll
        for (int ni = 0; ni < 4; ++ni) {
          float sv = sacc[mi][ni][r];
          if (diag) {
            int col = wc + ni * 16 + l15;
            if (col > row) { sv = NEGBIG; sacc[mi][ni][r] = sv; }
          }
          mx = fmaxf(mx, sv);
        }
#pragma unroll
        for (int off = 1; off < 16; off <<= 1)
          mx = fmaxf(mx, __shfl_xor(mx, off, 64));
        if (l15 == 0) red[w & 1][row] = mx;
      }
    }
    __syncthreads();
    if (tid < 128) {
      float tm = fmaxf(red[0][tid], red[1][tid]);
      float mo = m_sm[tid];
      float mn = fmaxf(mo, tm);
      m_sm[tid] = mn;
      a_sm[tid] = __expf(mo - mn);
    }
    __syncthreads();

    // P = exp(S - m), write to LDS (A-layout), rescale O, row-sum partials
#pragma unroll
    for (int mi = 0; mi < 4; ++mi) {
#pragma unroll
      for (int r = 0; r < 4; ++r) {
        int row = wr + mi * 16 + quad * 4 + r;
        float mn = m_sm[row];
        float al = a_sm[row];
        float rs = 0.f;
#pragma unroll
        for (int ni = 0; ni < 4; ++ni) {
          float p = __expf(sacc[mi][ni][r] - mn);
          rs += p;
          Ps[row * LQ + wc + ni * 16 + l15] = (bf16)p;
          oacc[mi][ni][r] *= al;
        }
#pragma unroll
        for (int off = 1; off < 16; off <<= 1)
          rs += __shfl_xor(rs, off, 64);
        if (l15 == 0) red[w & 1][row] = rs;
      }
    }
    __syncthreads();                   // Ps + sum partials visible
    if (tid < 128)
      l_sm[tid] = a_sm[tid] * l_sm[tid] + red[0][tid] + red[1][tid];

    // O += P @ V   (Vs is [hd][key] so B-frag reads are contiguous)
#pragma unroll
    for (int ks = 0; ks < 4; ++ks) {
      bf16x8 ap[4], bv[4];
#pragma unroll
      for (int mi = 0; mi < 4; ++mi)
        ap[mi] = *(const bf16x8*)(Ps + (wr + mi * 16 + l15) * LQ + ks * 32 + quad * 8);
#pragma unroll
      for (int ni = 0; ni < 4; ++ni)
        bv[ni] = *(const bf16x8*)(Vs + (wc + ni * 16 + l15) * LQ + ks * 32 + quad * 8);
#pragma unroll
      for (int mi = 0; mi < 4; ++mi)
#pragma unroll
        for (int ni = 0; ni < 4; ++ni)
          oacc[mi][ni] = __builtin_amdgcn_mfma_f32_16x16x32_bf16(
              ap[mi], bv[ni], oacc[mi][ni], 0, 0, 0);
    }
  }

  __syncthreads();
  if (tid < 128) a_sm[tid] = 1.0f / l_sm[tid];
  __syncthreads();

  // write attn output bf16 (s, h*HD + d)
#pragma unroll
  for (int mi = 0; mi < 4; ++mi) {
#pragma unroll
    for (int r = 0; r < 4; ++r) {
      int row = wr + mi * 16 + quad * 4 + r;
      float inv = a_sm[row];
#pragma unroll
      for (int ni = 0; ni < 4; ++ni)
        attnb[(size_t)(qbase + row) * DIM + h * HD + wc + ni * 16 + l15] =
            (bf16)(oacc[mi][ni][r] * inv);
    }
  }
}

// ---------------------------------------------------------------------------
extern "C" void kernel_launch(void* const* d_in, const int* in_sizes, int n_in,
                              void* d_out, int out_size, void* d_ws, size_t ws_size,
                              hipStream_t stream) {
  const float* x  = (const float*)d_in[0];
  const float* wq = (const float*)d_in[1];
  const float* wk = (const float*)d_in[2];
  const float* wv = (const float*)d_in[3];
  const float* wo = (const float*)d_in[4];
  const float* fc = (const float*)d_in[5];
  const float* fs = (const float*)d_in[6];
  // d_in[7] = mask, unused (causal handled analytically)
  float* out = (float*)d_out;

  size_t off = 0;
  char* wsb = (char*)d_ws;
  auto take = [&](size_t bytes) -> void* {
    void* p = wsb + off;
    off += (bytes + 255) & ~(size_t)255;
    return p;
  };
  bf16*  xb    = (bf16*)take((size_t)SEQ * DIM * 2);
  bf16*  wqb   = (bf16*)take((size_t)DIM * DIM * 2);
  bf16*  wkb   = (bf16*)take((size_t)KVD * DIM * 2);
  bf16*  wvb   = (bf16*)take((size_t)KVD * DIM * 2);
  bf16*  wob   = (bf16*)take((size_t)DIM * DIM * 2);
  float* Qf    = (float*)take((size_t)SEQ * DIM * 4);
  float* Kf    = (float*)take((size_t)SEQ * KVD * 4);
  float* Vf    = (float*)take((size_t)SEQ * KVD * 4);
  bf16*  Qb    = (bf16*)take((size_t)SEQ * DIM * 2);
  bf16*  Kb    = (bf16*)take((size_t)SEQ * KVD * 2);
  bf16*  Vt    = (bf16*)take((size_t)NKV * HD * SEQ * 2);
  bf16*  attnb = (bf16*)take((size_t)SEQ * DIM * 2);

  // casts
  cast_bf16_kernel<<<(SEQ * DIM / 4) / 256, 256, 0, stream>>>(x, xb, SEQ * DIM / 4);
  cast_bf16_kernel<<<(DIM * DIM / 4) / 256, 256, 0, stream>>>(wq, wqb, DIM * DIM / 4);
  cast_bf16_kernel<<<(KVD * DIM / 4) / 256, 256, 0, stream>>>(wk, wkb, KVD * DIM / 4);
  cast_bf16_kernel<<<(KVD * DIM / 4) / 256, 256, 0, stream>>>(wv, wvb, KVD * DIM / 4);
  cast_bf16_kernel<<<(DIM * DIM / 4) / 256, 256, 0, stream>>>(wo, wob, DIM * DIM / 4);

  // fused QKV projection (fp32 outputs)
  qkv_gemm_kernel<<<dim3(48, 16), 256, 0, stream>>>(xb, wqb, wkb, wvb, Qf, Kf, Vf);

  // RoPE + cast (Q folds softmax scale); V transpose to [kv][hd][s]
  rope_q_kernel<<<(SEQ * NH * 64) / 256, 256, 0, stream>>>(Qf, fc, fs, Qb);
  rope_k_kernel<<<(SEQ * NKV * 64) / 256, 256, 0, stream>>>(Kf, fc, fs, Kb);
  vtrans_kernel<<<dim3(SEQ / 32, HD / 32, NKV), dim3(32, 32), 0, stream>>>(Vf, Vt);

  // flash attention
  attn_kernel<<<dim3(16, 32), 256, 0, stream>>>(Qb, Kb, Vt, attnb);

  // output projection
  out_gemm_kernel<<<dim3(32, 16), 256, 0, stream>>>(attnb, wob, out);
}

// Round 2
// 517.950 us; speedup vs baseline: 1.4467x; 1.4467x over previous
//
#include <hip/hip_runtime.h>
#include <hip/hip_bf16.h>
#include <math.h>

// Problem constants
#define SEQ 2048
#define DIM 4096
#define NH 32
#define NKV 8
#define HD 128
#define KVD 1024              // NKV*HD
#define SCALE 0.08838834764831845f
#define NEGBIG -1000000000.0f

typedef __bf16 bf16;
typedef __attribute__((ext_vector_type(2))) __bf16 bf16x2;
typedef __attribute__((ext_vector_type(4))) __bf16 bf16x4;
typedef __attribute__((ext_vector_type(8))) __bf16 bf16x8;
typedef __attribute__((ext_vector_type(4))) float f32x4;

// ---------------------------------------------------------------------------
// async global->LDS 16B copy (wave-uniform LDS base + lane*16 semantics)
__device__ __forceinline__ void async_g2l16(const bf16* g, bf16* l) {
  __builtin_amdgcn_global_load_lds(
      (const __attribute__((address_space(1))) void*)g,
      (__attribute__((address_space(3))) void*)l,
      16, 0, 0);
}

// ---------------------------------------------------------------------------
// fp32 -> bf16 cast, float4 vectorized
__global__ void cast_bf16_kernel(const float* __restrict__ in,
                                 bf16* __restrict__ out, int n4) {
  int i = blockIdx.x * 256 + threadIdx.x;
  if (i >= n4) return;
  float4 v = ((const float4*)in)[i];
  bf16x4 o;
  o[0] = (bf16)v.x; o[1] = (bf16)v.y; o[2] = (bf16)v.z; o[3] = (bf16)v.w;
  ((bf16x4*)out)[i] = o;
}

// ---------------------------------------------------------------------------
// m97-style B^T GEMM body: C[M x N](fp32) = A[M x K](bf16,row-major) * B^T
// where B is [N x K] bf16 row-major. 128x128 tile, BK=32, 256 threads.
__device__ __forceinline__ void gemm_bt_body(
    const bf16* __restrict__ A, int lda,
    const bf16* __restrict__ B, int ldb,
    float* __restrict__ C, int ldc,
    int K, int mBase)
{
  __shared__ __align__(16) bf16 As[128 * 32];
  __shared__ __align__(16) bf16 Bs[128 * 32];

  const int tid  = threadIdx.x;
  const int lane = tid & 63;
  const int w    = tid >> 6;
  const int l15  = lane & 15;
  const int quad = lane >> 4;
  const int wr   = (w >> 1) * 64;
  const int wc   = (w & 1) * 64;

  const int srow = lane >> 2;          // 0..15 within chunk
  const int skp  = (lane & 3) * 8;     // 0,8,16,24 elements within 32-wide k
  const bf16* gA0 = A + (size_t)(mBase + w * 16 + srow) * lda + skp;
  const bf16* gA1 = gA0 + (size_t)64 * lda;
  const bf16* gB0 = B + (size_t)(w * 16 + srow) * ldb + skp;
  const bf16* gB1 = gB0 + (size_t)64 * ldb;
  bf16* lA0 = As + w * 512;
  bf16* lA1 = As + (w + 4) * 512;
  bf16* lB0 = Bs + w * 512;
  bf16* lB1 = Bs + (w + 4) * 512;

  const f32x4 vzero = {0.f, 0.f, 0.f, 0.f};
  f32x4 acc[4][4];
#pragma unroll
  for (int mi = 0; mi < 4; ++mi)
#pragma unroll
    for (int ni = 0; ni < 4; ++ni) acc[mi][ni] = vzero;

  for (int k0 = 0; k0 < K; k0 += 32) {
    __syncthreads();
    async_g2l16(gA0 + k0, lA0);
    async_g2l16(gA1 + k0, lA1);
    async_g2l16(gB0 + k0, lB0);
    async_g2l16(gB1 + k0, lB1);
    __syncthreads();

    bf16x8 a[4], b[4];
#pragma unroll
    for (int mi = 0; mi < 4; ++mi)
      a[mi] = *(const bf16x8*)(As + (wr + mi * 16 + l15) * 32 + quad * 8);
#pragma unroll
    for (int ni = 0; ni < 4; ++ni)
      b[ni] = *(const bf16x8*)(Bs + (wc + ni * 16 + l15) * 32 + quad * 8);
#pragma unroll
    for (int mi = 0; mi < 4; ++mi)
#pragma unroll
      for (int ni = 0; ni < 4; ++ni)
        acc[mi][ni] = __builtin_amdgcn_mfma_f32_16x16x32_bf16(
            a[mi], b[ni], acc[mi][ni], 0, 0, 0);
  }

#pragma unroll
  for (int mi = 0; mi < 4; ++mi) {
    int row = mBase + wr + mi * 16 + quad * 4;
#pragma unroll
    for (int ni = 0; ni < 4; ++ni) {
      int col = wc + ni * 16 + l15;
#pragma unroll
      for (int r = 0; r < 4; ++r)
        C[(size_t)(row + r) * ldc + col] = acc[mi][ni][r];
    }
  }
}

// QKV projection: x(2048x4096) @ {wq,wk,wv}^T -> Qf, Kf, Vf (fp32)
__global__ __launch_bounds__(256, 2) void qkv_gemm_kernel(
    const bf16* __restrict__ xb, const bf16* __restrict__ wqb,
    const bf16* __restrict__ wkb, const bf16* __restrict__ wvb,
    float* __restrict__ Qf, float* __restrict__ Kf, float* __restrict__ Vf)
{
  int nb = blockIdx.x;                 // 0..47: 32 Q blocks, 8 K, 8 V
  const bf16* B; float* C; int ldc;
  if (nb < 32)      { B = wqb + (size_t)nb * 128 * DIM;        C = Qf + nb * 128;        ldc = DIM; }
  else if (nb < 40) { int t = nb - 32; B = wkb + (size_t)t * 128 * DIM; C = Kf + t * 128; ldc = KVD; }
  else              { int t = nb - 40; B = wvb + (size_t)t * 128 * DIM; C = Vf + t * 128; ldc = KVD; }
  gemm_bt_body(xb, DIM, B, DIM, C, ldc, DIM, blockIdx.y * 128);
}

// Output projection: attn(2048x4096 bf16) @ wo^T -> out (fp32)
__global__ __launch_bounds__(256, 2) void out_gemm_kernel(
    const bf16* __restrict__ attnb, const bf16* __restrict__ wob,
    float* __restrict__ out)
{
  gemm_bt_body(attnb, DIM, wob + (size_t)blockIdx.x * 128 * DIM, DIM,
               out + blockIdx.x * 128, DIM, DIM, blockIdx.y * 128);
}

// ---------------------------------------------------------------------------
// RoPE (interleaved pairs) + bf16 cast; Q also folds in 1/sqrt(HD).
__global__ void rope_q_kernel(const float* __restrict__ Qf,
                              const float* __restrict__ Cb,
                              const float* __restrict__ Sb,
                              bf16* __restrict__ Qb) {
  int i = blockIdx.x * 256 + threadIdx.x;    // S*NH*64 threads
  int di = i & 63;
  int h  = (i >> 6) & (NH - 1);
  int s  = i >> 11;
  size_t base = (size_t)s * DIM + h * HD + 2 * di;
  float2 t = *(const float2*)(Qf + base);
  float c = Cb[s * 64 + di], sn = Sb[s * 64 + di];
  bf16x2 o;
  o[0] = (bf16)((t.x * c - t.y * sn) * SCALE);
  o[1] = (bf16)((t.x * sn + t.y * c) * SCALE);
  *(bf16x2*)(Qb + base) = o;
}

__global__ void rope_k_kernel(const float* __restrict__ Kf,
                              const float* __restrict__ Cb,
                              const float* __restrict__ Sb,
                              bf16* __restrict__ Kb) {
  int i = blockIdx.x * 256 + threadIdx.x;    // S*NKV*64 threads
  int di = i & 63;
  int h  = (i >> 6) & (NKV - 1);
  int s  = i >> 9;
  size_t base = (size_t)s * KVD + h * HD + 2 * di;
  float2 t = *(const float2*)(Kf + base);
  float c = Cb[s * 64 + di], sn = Sb[s * 64 + di];
  bf16x2 o;
  o[0] = (bf16)(t.x * c - t.y * sn);
  o[1] = (bf16)(t.x * sn + t.y * c);
  *(bf16x2*)(Kb + base) = o;
}

// V transpose+cast: Vf (s, kv*128+d) fp32 -> Vt [kv][d][s] bf16
__global__ void vtrans_kernel(const float* __restrict__ Vf,
                              bf16* __restrict__ Vt) {
  __shared__ float tile[32][33];
  int kv = blockIdx.z;
  int d0 = blockIdx.y * 32, s0 = blockIdx.x * 32;
  int tx = threadIdx.x, ty = threadIdx.y;
  tile[ty][tx] = Vf[(size_t)(s0 + ty) * KVD + kv * HD + d0 + tx];
  __syncthreads();
  Vt[(size_t)kv * HD * SEQ + (size_t)(d0 + ty) * SEQ + s0 + tx] =
      (bf16)tile[tx][ty];
}

// ---------------------------------------------------------------------------
// Flash attention v2: transposed scores (St = K @ Q^T).
//  - wave w owns queries [w*32, w*32+32) of a 128-query tile (2 n-tiles)
//  - Q frags in registers (loaded once); softmax m/l in registers
//  - P round-trip through wave-private Ps with packed b64 writes
//  - K/V staged with global_load_lds(16B) into XOR-swizzled LDS (no pads,
//    conflict-free reads); only 2 barriers per kt iteration
//  - Kt=64 keys/iter; LDS = 48 KB -> 2 blocks/CU
__global__ __launch_bounds__(256, 2) void attn_kernel(
    const bf16* __restrict__ Qb, const bf16* __restrict__ Kb,
    const bf16* __restrict__ Vt, bf16* __restrict__ attnb)
{
  __shared__ __align__(16) bf16 Ks[64 * 128];   // [key][hd], swizzled 16B grps
  __shared__ __align__(16) bf16 Vs[128 * 64];   // [hd][key], swizzled
  __shared__ __align__(16) bf16 Ps[128 * 64];   // [query][key], swizzled

  // grid: 512 linear blocks; pair big qt with small qt across halves
  const int b    = blockIdx.x;
  const int half = b >> 8;
  const int r8   = b & 255;
  const int h    = (half << 4) | (r8 >> 4);
  const int qt   = half ? (r8 & 15) : 15 - (r8 & 15);
  const int kvh  = h >> 2;
  const int qbase = qt * 128;

  const int tid  = threadIdx.x;
  const int lane = tid & 63;
  const int w    = tid >> 6;
  const int l15  = lane & 15;
  const int quad = lane >> 4;

  // Q fragments in registers: B-operand frags, lane holds query q0+l15,
  // k = ks*32 + quad*8 + j  (scale pre-folded into Qb)
  bf16x8 qfrag[2][4];
#pragma unroll
  for (int n = 0; n < 2; ++n) {
    int q = qbase + w * 32 + n * 16 + l15;
#pragma unroll
    for (int ks = 0; ks < 4; ++ks)
      qfrag[n][ks] = *(const bf16x8*)(Qb + (size_t)q * DIM + h * HD +
                                      ks * 32 + quad * 8);
  }

  const f32x4 vzero = {0.f, 0.f, 0.f, 0.f};
  f32x4 oacc[8][2];                    // [d-tile][n], O^T accumulator
#pragma unroll
  for (int dm = 0; dm < 8; ++dm)
#pragma unroll
    for (int n = 0; n < 2; ++n) oacc[dm][n] = vzero;
  float m_run[2] = {-1e30f, -1e30f};
  float l_run[2] = {0.f, 0.f};

  const int nkt = 2 * (qt + 1);        // 64-key steps
  for (int kt = 0; kt < nkt; ++kt) {
    const int kbase = kt * 64;

    __syncthreads();                   // prior iter's Ks/Vs reads complete
    // stage K tile (64 rows x 256B) + V tile (128 rows x 128B), swizzled
#pragma unroll
    for (int t = 0; t < 4; ++t) {
      int kr0 = w * 16 + t * 4;
      int krow = kr0 + (lane >> 4);
      int kg = (lane & 15) ^ (krow & 7);
      async_g2l16(Kb + (size_t)(kbase + krow) * KVD + kvh * HD + kg * 8,
                  Ks + kr0 * 128);
      int vr0 = w * 32 + t * 8;
      int d = vr0 + (lane >> 3);
      int vg = (lane & 7) ^ (d & 7);
      async_g2l16(Vt + ((size_t)kvh * HD + d) * SEQ + kbase + vg * 8,
                  Vs + vr0 * 64);
    }
    __syncthreads();                   // staged (vmcnt(0) drained)

    // St = K @ Q^T : St[key][query]; C-frag: query=l15, key=quad*4+r
    f32x4 sacc[4][2];
#pragma unroll
    for (int kg = 0; kg < 4; ++kg)
#pragma unroll
      for (int n = 0; n < 2; ++n) sacc[kg][n] = vzero;
#pragma unroll
    for (int kg = 0; kg < 4; ++kg) {
      bf16x8 kf[4];
#pragma unroll
      for (int ks = 0; ks < 4; ++ks) {
        int row = kg * 16 + l15;
        kf[ks] = *(const bf16x8*)(Ks + row * 128 +
                                  (((ks * 4 + quad) ^ (row & 7)) * 8));
      }
#pragma unroll
      for (int n = 0; n < 2; ++n)
#pragma unroll
        for (int ks = 0; ks < 4; ++ks)
          sacc[kg][n] = __builtin_amdgcn_mfma_f32_16x16x32_bf16(
              kf[ks], qfrag[n][ks], sacc[kg][n], 0, 0, 0);
    }

    // online softmax per query column (register m/l, 2 shuffles per reduce)
#pragma unroll
    for (int n = 0; n < 2; ++n) {
      const int qloc = w * 32 + n * 16 + l15;
      const int qglob = qbase + qloc;
      if (kbase + 63 > qbase + w * 32 + n * 16) {   // causal mask needed
#pragma unroll
        for (int kg = 0; kg < 4; ++kg)
#pragma unroll
          for (int r = 0; r < 4; ++r) {
            int key = kbase + kg * 16 + quad * 4 + r;
            if (key > qglob) sacc[kg][n][r] = NEGBIG;
          }
      }
      float mx = -1e30f;
#pragma unroll
      for (int kg = 0; kg < 4; ++kg)
#pragma unroll
        for (int r = 0; r < 4; ++r) mx = fmaxf(mx, sacc[kg][n][r]);
      mx = fmaxf(mx, __shfl_xor(mx, 16, 64));
      mx = fmaxf(mx, __shfl_xor(mx, 32, 64));
      float mnew = fmaxf(m_run[n], mx);
      float alpha = __expf(m_run[n] - mnew);
      m_run[n] = mnew;
      float rs = 0.f;
#pragma unroll
      for (int kg = 0; kg < 4; ++kg) {
        bf16x4 pk;
#pragma unroll
        for (int r = 0; r < 4; ++r) {
          float p = __expf(sacc[kg][n][r] - mnew);
          rs += p;
          pk[r] = (bf16)p;
        }
        // packed b64 write: 4 consecutive keys, swizzled layout
        int g16 = (kg * 2 + (quad >> 1)) ^ (qloc & 7);
        *(bf16x4*)(Ps + qloc * 64 + g16 * 8 + (quad & 1) * 4) = pk;
      }
      rs += __shfl_xor(rs, 16, 64);
      rs += __shfl_xor(rs, 32, 64);
      l_run[n] = alpha * l_run[n] + rs;
#pragma unroll
      for (int dm = 0; dm < 8; ++dm)
#pragma unroll
        for (int r = 0; r < 4; ++r) oacc[dm][n][r] *= alpha;
    }

    // O^T += V^T @ P^T  (A = Vs rows d, B = Ps rows query; wave-private)
    bf16x8 pf[2][2];
#pragma unroll
    for (int kk = 0; kk < 2; ++kk)
#pragma unroll
      for (int n = 0; n < 2; ++n) {
        int qloc = w * 32 + n * 16 + l15;
        pf[kk][n] = *(const bf16x8*)(Ps + qloc * 64 +
                                     (((kk * 4 + quad) ^ (qloc & 7)) * 8));
      }
#pragma unroll
    for (int dm = 0; dm < 8; ++dm) {
#pragma unroll
      for (int kk = 0; kk < 2; ++kk) {
        int d = dm * 16 + l15;
        bf16x8 vf = *(const bf16x8*)(Vs + d * 64 +
                                     (((kk * 4 + quad) ^ (d & 7)) * 8));
#pragma unroll
        for (int n = 0; n < 2; ++n)
          oacc[dm][n] = __builtin_amdgcn_mfma_f32_16x16x32_bf16(
              vf, pf[kk][n], oacc[dm][n], 0, 0, 0);
      }
    }
  }

  // epilogue: O^T frag col=l15=query, row=quad*4+r=d -> pack 4 d's per store
#pragma unroll
  for (int n = 0; n < 2; ++n) {
    float inv = 1.0f / l_run[n];
    int q = qbase + w * 32 + n * 16 + l15;
#pragma unroll
    for (int dm = 0; dm < 8; ++dm) {
      bf16x4 ov;
#pragma unroll
      for (int r = 0; r < 4; ++r) ov[r] = (bf16)(oacc[dm][n][r] * inv);
      *(bf16x4*)(attnb + (size_t)q * DIM + h * HD + dm * 16 + quad * 4) = ov;
    }
  }
}

// ---------------------------------------------------------------------------
extern "C" void kernel_launch(void* const* d_in, const int* in_sizes, int n_in,
                              void* d_out, int out_size, void* d_ws, size_t ws_size,
                              hipStream_t stream) {
  const float* x  = (const float*)d_in[0];
  const float* wq = (const float*)d_in[1];
  const float* wk = (const float*)d_in[2];
  const float* wv = (const float*)d_in[3];
  const float* wo = (const float*)d_in[4];
  const float* fc = (const float*)d_in[5];
  const float* fs = (const float*)d_in[6];
  float* out = (float*)d_out;

  size_t off = 0;
  char* wsb = (char*)d_ws;
  auto take = [&](size_t bytes) -> void* {
    void* p = wsb + off;
    off += (bytes + 255) & ~(size_t)255;
    return p;
  };
  bf16*  xb    = (bf16*)take((size_t)SEQ * DIM * 2);
  bf16*  wqb   = (bf16*)take((size_t)DIM * DIM * 2);
  bf16*  wkb   = (bf16*)take((size_t)KVD * DIM * 2);
  bf16*  wvb   = (bf16*)take((size_t)KVD * DIM * 2);
  bf16*  wob   = (bf16*)take((size_t)DIM * DIM * 2);
  float* Qf    = (float*)take((size_t)SEQ * DIM * 4);
  float* Kf    = (float*)take((size_t)SEQ * KVD * 4);
  float* Vf    = (float*)take((size_t)SEQ * KVD * 4);
  bf16*  Qb    = (bf16*)take((size_t)SEQ * DIM * 2);
  bf16*  Kb    = (bf16*)take((size_t)SEQ * KVD * 2);
  bf16*  Vt    = (bf16*)take((size_t)NKV * HD * SEQ * 2);
  bf16*  attnb = (bf16*)take((size_t)SEQ * DIM * 2);

  // casts
  cast_bf16_kernel<<<(SEQ * DIM / 4) / 256, 256, 0, stream>>>(x, xb, SEQ * DIM / 4);
  cast_bf16_kernel<<<(DIM * DIM / 4) / 256, 256, 0, stream>>>(wq, wqb, DIM * DIM / 4);
  cast_bf16_kernel<<<(KVD * DIM / 4) / 256, 256, 0, stream>>>(wk, wkb, KVD * DIM / 4);
  cast_bf16_kernel<<<(KVD * DIM / 4) / 256, 256, 0, stream>>>(wv, wvb, KVD * DIM / 4);
  cast_bf16_kernel<<<(DIM * DIM / 4) / 256, 256, 0, stream>>>(wo, wob, DIM * DIM / 4);

  // fused QKV projection (fp32 outputs)
  qkv_gemm_kernel<<<dim3(48, 16), 256, 0, stream>>>(xb, wqb, wkb, wvb, Qf, Kf, Vf);

  // RoPE + cast (Q folds softmax scale); V transpose to [kv][hd][s]
  rope_q_kernel<<<(SEQ * NH * 64) / 256, 256, 0, stream>>>(Qf, fc, fs, Qb);
  rope_k_kernel<<<(SEQ * NKV * 64) / 256, 256, 0, stream>>>(Kf, fc, fs, Kb);
  vtrans_kernel<<<dim3(SEQ / 32, HD / 32, NKV), dim3(32, 32), 0, stream>>>(Vf, Vt);

  // flash attention (512 linear blocks, big/small qt pairing)
  attn_kernel<<<dim3(512), 256, 0, stream>>>(Qb, Kb, Vt, attnb);

  // output projection
  out_gemm_kernel<<<dim3(32, 16), 256, 0, stream>>>(attnb, wob, out);
}

// Round 3
// 483.104 us; speedup vs baseline: 1.5510x; 1.0721x over previous
//
#include <hip/hip_runtime.h>
#include <hip/hip_bf16.h>
#include <math.h>

// Problem constants
#define SEQ 2048
#define DIM 4096
#define NH 32
#define NKV 8
#define HD 128
#define KVD 1024              // NKV*HD
#define SCALE 0.08838834764831845f
#define NEGBIG -1000000000.0f

typedef __bf16 bf16;
typedef __attribute__((ext_vector_type(2))) __bf16 bf16x2;
typedef __attribute__((ext_vector_type(4))) __bf16 bf16x4;
typedef __attribute__((ext_vector_type(8))) __bf16 bf16x8;
typedef __attribute__((ext_vector_type(4))) float f32x4;

// ---------------------------------------------------------------------------
// async global->LDS 16B copy (wave-uniform LDS base + lane*16 semantics)
__device__ __forceinline__ void async_g2l16(const bf16* g, bf16* l) {
  __builtin_amdgcn_global_load_lds(
      (const __attribute__((address_space(1))) void*)g,
      (__attribute__((address_space(3))) void*)l,
      16, 0, 0);
}

// ---------------------------------------------------------------------------
// fused fp32 -> bf16 cast for all 5 tensors, float4 vectorized, 1 launch
#define SEG_X  2097152            // SEQ*DIM/4
#define SEG_WQ 4194304            // DIM*DIM/4
#define SEG_WK 1048576            // KVD*DIM/4
#define C0 SEG_X
#define C1 (C0 + SEG_WQ)
#define C2 (C1 + SEG_WK)
#define C3 (C2 + SEG_WK)
#define C4 (C3 + SEG_WQ)          // 12582912 total float4

__global__ void cast_all_kernel(const float* __restrict__ x,
                                const float* __restrict__ wq,
                                const float* __restrict__ wk,
                                const float* __restrict__ wv,
                                const float* __restrict__ wo,
                                bf16* __restrict__ xb, bf16* __restrict__ wqb,
                                bf16* __restrict__ wkb, bf16* __restrict__ wvb,
                                bf16* __restrict__ wob) {
  int i = blockIdx.x * 256 + threadIdx.x;
  const float* src; bf16* dst; int j;
  if (i < C0)      { src = x;  dst = xb;  j = i; }
  else if (i < C1) { src = wq; dst = wqb; j = i - C0; }
  else if (i < C2) { src = wk; dst = wkb; j = i - C1; }
  else if (i < C3) { src = wv; dst = wvb; j = i - C2; }
  else             { src = wo; dst = wob; j = i - C3; }
  float4 v = ((const float4*)src)[j];
  bf16x4 o;
  o[0] = (bf16)v.x; o[1] = (bf16)v.y; o[2] = (bf16)v.z; o[3] = (bf16)v.w;
  ((bf16x4*)dst)[j] = o;
}

// ---------------------------------------------------------------------------
// m97-style B^T GEMM core with XOR-swizzled LDS (conflict-free b128 reads):
// LDS[row][g] holds global k-group g ^ ((row>>1)&3). Swizzle is applied to
// the GLOBAL source address at staging (wave-uniform LDS dest preserved)
// and undone at fragment read (involution).
__device__ __forceinline__ void gemm_core(
    const bf16* __restrict__ A, int lda,
    const bf16* __restrict__ B, int ldb,
    int K, int mBase, f32x4 acc[4][4])
{
  __shared__ __align__(16) bf16 As[128 * 32];
  __shared__ __align__(16) bf16 Bs[128 * 32];

  const int tid  = threadIdx.x;
  const int lane = tid & 63;
  const int w    = tid >> 6;
  const int l15  = lane & 15;
  const int quad = lane >> 4;
  const int wr   = (w >> 1) * 64;
  const int wc   = (w & 1) * 64;

  const int srow = lane >> 2;                      // 0..15 within chunk
  const int kswz = ((lane & 3) ^ ((srow >> 1) & 3)) * 8;  // swizzled k-group
  const bf16* gA0 = A + (size_t)(mBase + w * 16 + srow) * lda + kswz;
  const bf16* gA1 = gA0 + (size_t)64 * lda;
  const bf16* gB0 = B + (size_t)(w * 16 + srow) * ldb + kswz;
  const bf16* gB1 = gB0 + (size_t)64 * ldb;
  bf16* lA0 = As + w * 512;
  bf16* lA1 = As + (w + 4) * 512;
  bf16* lB0 = Bs + w * 512;
  bf16* lB1 = Bs + (w + 4) * 512;

  const f32x4 vzero = {0.f, 0.f, 0.f, 0.f};
#pragma unroll
  for (int mi = 0; mi < 4; ++mi)
#pragma unroll
    for (int ni = 0; ni < 4; ++ni) acc[mi][ni] = vzero;

  const int rsw = ((l15 >> 1) & 3);                // read-side swizzle term

  for (int k0 = 0; k0 < K; k0 += 32) {
    __syncthreads();
    async_g2l16(gA0 + k0, lA0);
    async_g2l16(gA1 + k0, lA1);
    async_g2l16(gB0 + k0, lB0);
    async_g2l16(gB1 + k0, lB1);
    __syncthreads();

    bf16x8 a[4], b[4];
#pragma unroll
    for (int mi = 0; mi < 4; ++mi)
      a[mi] = *(const bf16x8*)(As + (wr + mi * 16 + l15) * 32 +
                               ((quad ^ rsw) * 8));
#pragma unroll
    for (int ni = 0; ni < 4; ++ni)
      b[ni] = *(const bf16x8*)(Bs + (wc + ni * 16 + l15) * 32 +
                               ((quad ^ rsw) * 8));
#pragma unroll
    for (int mi = 0; mi < 4; ++mi)
#pragma unroll
      for (int ni = 0; ni < 4; ++ni)
        acc[mi][ni] = __builtin_amdgcn_mfma_f32_16x16x32_bf16(
            a[mi], b[ni], acc[mi][ni], 0, 0, 0);
  }
}

// ---------------------------------------------------------------------------
// QKV projection with fused RoPE/scale/cast/V-transpose epilogue.
// nb<32: Q head nb -> Qb (roped, *SCALE, bf16)
// nb<40: K kv-head nb-32 -> Kb (roped, bf16)
// else : V kv-head nb-40 -> Vt [kv][d][s] (bf16, transposed)
__global__ __launch_bounds__(256, 2) void qkv_gemm_kernel(
    const bf16* __restrict__ xb, const bf16* __restrict__ wqb,
    const bf16* __restrict__ wkb, const bf16* __restrict__ wvb,
    const float* __restrict__ fc, const float* __restrict__ fs,
    bf16* __restrict__ Qb, bf16* __restrict__ Kb, bf16* __restrict__ Vt)
{
  const int nb = blockIdx.x;
  const int mBase = blockIdx.y * 128;
  const bf16* Bm;
  if (nb < 32)      Bm = wqb + (size_t)nb * 128 * DIM;
  else if (nb < 40) Bm = wkb + (size_t)(nb - 32) * 128 * DIM;
  else              Bm = wvb + (size_t)(nb - 40) * 128 * DIM;

  f32x4 acc[4][4];
  gemm_core(xb, DIM, Bm, DIM, DIM, mBase, acc);

  const int tid  = threadIdx.x;
  const int lane = tid & 63;
  const int w    = tid >> 6;
  const int l15  = lane & 15;
  const int quad = lane >> 4;
  const int wr   = (w >> 1) * 64;
  const int wc   = (w & 1) * 64;

  if (nb < 40) {
    // RoPE: d and d^1 live in adjacent lanes (l15 bit0) -> shfl_xor(1)
    const bool isQ = (nb < 32);
    bf16* dst = isQ ? (Qb + nb * HD) : (Kb + (nb - 32) * HD);
    const int ldd = isQ ? DIM : KVD;
    const float sc = isQ ? SCALE : 1.0f;
    const int odd = l15 & 1;
#pragma unroll
    for (int mi = 0; mi < 4; ++mi) {
#pragma unroll
      for (int ni = 0; ni < 4; ++ni) {
        int d = wc + ni * 16 + l15;
        int fidx = d >> 1;
#pragma unroll
        for (int r = 0; r < 4; ++r) {
          int s = mBase + wr + mi * 16 + quad * 4 + r;
          float v  = acc[mi][ni][r];
          float pv = __shfl_xor(v, 1, 64);
          float c  = fc[s * 64 + fidx];
          float sn = fs[s * 64 + fidx];
          float o  = odd ? (pv * sn + v * c) : (v * c - pv * sn);
          dst[(size_t)s * ldd + d] = (bf16)(o * sc);
        }
      }
    }
  } else {
    // V: transpose to [kv][d][s]; 4 consecutive rows (s) -> bf16x4 store
    const int t = nb - 40;
#pragma unroll
    for (int mi = 0; mi < 4; ++mi) {
      int srow = mBase + wr + mi * 16 + quad * 4;
#pragma unroll
      for (int ni = 0; ni < 4; ++ni) {
        int d = wc + ni * 16 + l15;
        bf16x4 pv;
#pragma unroll
        for (int r = 0; r < 4; ++r) pv[r] = (bf16)acc[mi][ni][r];
        *(bf16x4*)(Vt + ((size_t)t * HD + d) * SEQ + srow) = pv;
      }
    }
  }
}

// Output projection: attn(2048x4096 bf16) @ wo^T -> out (fp32)
__global__ __launch_bounds__(256, 2) void out_gemm_kernel(
    const bf16* __restrict__ attnb, const bf16* __restrict__ wob,
    float* __restrict__ out)
{
  const int mBase = blockIdx.y * 128;
  f32x4 acc[4][4];
  gemm_core(attnb, DIM, wob + (size_t)blockIdx.x * 128 * DIM, DIM, DIM,
            mBase, acc);

  const int tid  = threadIdx.x;
  const int lane = tid & 63;
  const int w    = tid >> 6;
  const int l15  = lane & 15;
  const int quad = lane >> 4;
  const int wr   = (w >> 1) * 64;
  const int wc   = (w & 1) * 64;
#pragma unroll
  for (int mi = 0; mi < 4; ++mi) {
    int row = mBase + wr + mi * 16 + quad * 4;
#pragma unroll
    for (int ni = 0; ni < 4; ++ni) {
      int col = blockIdx.x * 128 + wc + ni * 16 + l15;
#pragma unroll
      for (int r = 0; r < 4; ++r)
        out[(size_t)(row + r) * DIM + col] = acc[mi][ni][r];
    }
  }
}

// ---------------------------------------------------------------------------
// Flash attention: transposed scores (St = K @ Q^T). Unchanged from R2.
__global__ __launch_bounds__(256, 2) void attn_kernel(
    const bf16* __restrict__ Qb, const bf16* __restrict__ Kb,
    const bf16* __restrict__ Vt, bf16* __restrict__ attnb)
{
  __shared__ __align__(16) bf16 Ks[64 * 128];   // [key][hd], swizzled 16B grps
  __shared__ __align__(16) bf16 Vs[128 * 64];   // [hd][key], swizzled
  __shared__ __align__(16) bf16 Ps[128 * 64];   // [query][key], swizzled

  const int b    = blockIdx.x;
  const int half = b >> 8;
  const int r8   = b & 255;
  const int h    = (half << 4) | (r8 >> 4);
  const int qt   = half ? (r8 & 15) : 15 - (r8 & 15);
  const int kvh  = h >> 2;
  const int qbase = qt * 128;

  const int tid  = threadIdx.x;
  const int lane = tid & 63;
  const int w    = tid >> 6;
  const int l15  = lane & 15;
  const int quad = lane >> 4;

  bf16x8 qfrag[2][4];
#pragma unroll
  for (int n = 0; n < 2; ++n) {
    int q = qbase + w * 32 + n * 16 + l15;
#pragma unroll
    for (int ks = 0; ks < 4; ++ks)
      qfrag[n][ks] = *(const bf16x8*)(Qb + (size_t)q * DIM + h * HD +
                                      ks * 32 + quad * 8);
  }

  const f32x4 vzero = {0.f, 0.f, 0.f, 0.f};
  f32x4 oacc[8][2];
#pragma unroll
  for (int dm = 0; dm < 8; ++dm)
#pragma unroll
    for (int n = 0; n < 2; ++n) oacc[dm][n] = vzero;
  float m_run[2] = {-1e30f, -1e30f};
  float l_run[2] = {0.f, 0.f};

  const int nkt = 2 * (qt + 1);
  for (int kt = 0; kt < nkt; ++kt) {
    const int kbase = kt * 64;

    __syncthreads();
#pragma unroll
    for (int t = 0; t < 4; ++t) {
      int kr0 = w * 16 + t * 4;
      int krow = kr0 + (lane >> 4);
      int kg = (lane & 15) ^ (krow & 7);
      async_g2l16(Kb + (size_t)(kbase + krow) * KVD + kvh * HD + kg * 8,
                  Ks + kr0 * 128);
      int vr0 = w * 32 + t * 8;
      int d = vr0 + (lane >> 3);
      int vg = (lane & 7) ^ (d & 7);
      async_g2l16(Vt + ((size_t)kvh * HD + d) * SEQ + kbase + vg * 8,
                  Vs + vr0 * 64);
    }
    __syncthreads();

    f32x4 sacc[4][2];
#pragma unroll
    for (int kg = 0; kg < 4; ++kg)
#pragma unroll
      for (int n = 0; n < 2; ++n) sacc[kg][n] = vzero;
#pragma unroll
    for (int kg = 0; kg < 4; ++kg) {
      bf16x8 kf[4];
#pragma unroll
      for (int ks = 0; ks < 4; ++ks) {
        int row = kg * 16 + l15;
        kf[ks] = *(const bf16x8*)(Ks + row * 128 +
                                  (((ks * 4 + quad) ^ (row & 7)) * 8));
      }
#pragma unroll
      for (int n = 0; n < 2; ++n)
#pragma unroll
        for (int ks = 0; ks < 4; ++ks)
          sacc[kg][n] = __builtin_amdgcn_mfma_f32_16x16x32_bf16(
              kf[ks], qfrag[n][ks], sacc[kg][n], 0, 0, 0);
    }

#pragma unroll
    for (int n = 0; n < 2; ++n) {
      const int qloc = w * 32 + n * 16 + l15;
      const int qglob = qbase + qloc;
      if (kbase + 63 > qbase + w * 32 + n * 16) {
#pragma unroll
        for (int kg = 0; kg < 4; ++kg)
#pragma unroll
          for (int r = 0; r < 4; ++r) {
            int key = kbase + kg * 16 + quad * 4 + r;
            if (key > qglob) sacc[kg][n][r] = NEGBIG;
          }
      }
      float mx = -1e30f;
#pragma unroll
      for (int kg = 0; kg < 4; ++kg)
#pragma unroll
        for (int r = 0; r < 4; ++r) mx = fmaxf(mx, sacc[kg][n][r]);
      mx = fmaxf(mx, __shfl_xor(mx, 16, 64));
      mx = fmaxf(mx, __shfl_xor(mx, 32, 64));
      float mnew = fmaxf(m_run[n], mx);
      float alpha = __expf(m_run[n] - mnew);
      m_run[n] = mnew;
      float rs = 0.f;
#pragma unroll
      for (int kg = 0; kg < 4; ++kg) {
        bf16x4 pk;
#pragma unroll
        for (int r = 0; r < 4; ++r) {
          float p = __expf(sacc[kg][n][r] - mnew);
          rs += p;
          pk[r] = (bf16)p;
        }
        int g16 = (kg * 2 + (quad >> 1)) ^ (qloc & 7);
        *(bf16x4*)(Ps + qloc * 64 + g16 * 8 + (quad & 1) * 4) = pk;
      }
      rs += __shfl_xor(rs, 16, 64);
      rs += __shfl_xor(rs, 32, 64);
      l_run[n] = alpha * l_run[n] + rs;
#pragma unroll
      for (int dm = 0; dm < 8; ++dm)
#pragma unroll
        for (int r = 0; r < 4; ++r) oacc[dm][n][r] *= alpha;
    }

    bf16x8 pf[2][2];
#pragma unroll
    for (int kk = 0; kk < 2; ++kk)
#pragma unroll
      for (int n = 0; n < 2; ++n) {
        int qloc = w * 32 + n * 16 + l15;
        pf[kk][n] = *(const bf16x8*)(Ps + qloc * 64 +
                                     (((kk * 4 + quad) ^ (qloc & 7)) * 8));
      }
#pragma unroll
    for (int dm = 0; dm < 8; ++dm) {
#pragma unroll
      for (int kk = 0; kk < 2; ++kk) {
        int d = dm * 16 + l15;
        bf16x8 vf = *(const bf16x8*)(Vs + d * 64 +
                                     (((kk * 4 + quad) ^ (d & 7)) * 8));
#pragma unroll
        for (int n = 0; n < 2; ++n)
          oacc[dm][n] = __builtin_amdgcn_mfma_f32_16x16x32_bf16(
              vf, pf[kk][n], oacc[dm][n], 0, 0, 0);
      }
    }
  }

#pragma unroll
  for (int n = 0; n < 2; ++n) {
    float inv = 1.0f / l_run[n];
    int q = qbase + w * 32 + n * 16 + l15;
#pragma unroll
    for (int dm = 0; dm < 8; ++dm) {
      bf16x4 ov;
#pragma unroll
      for (int r = 0; r < 4; ++r) ov[r] = (bf16)(oacc[dm][n][r] * inv);
      *(bf16x4*)(attnb + (size_t)q * DIM + h * HD + dm * 16 + quad * 4) = ov;
    }
  }
}

// ---------------------------------------------------------------------------
extern "C" void kernel_launch(void* const* d_in, const int* in_sizes, int n_in,
                              void* d_out, int out_size, void* d_ws, size_t ws_size,
                              hipStream_t stream) {
  const float* x  = (const float*)d_in[0];
  const float* wq = (const float*)d_in[1];
  const float* wk = (const float*)d_in[2];
  const float* wv = (const float*)d_in[3];
  const float* wo = (const float*)d_in[4];
  const float* fc = (const float*)d_in[5];
  const float* fs = (const float*)d_in[6];
  float* out = (float*)d_out;

  size_t off = 0;
  char* wsb = (char*)d_ws;
  auto take = [&](size_t bytes) -> void* {
    void* p = wsb + off;
    off += (bytes + 255) & ~(size_t)255;
    return p;
  };
  bf16*  xb    = (bf16*)take((size_t)SEQ * DIM * 2);
  bf16*  wqb   = (bf16*)take((size_t)DIM * DIM * 2);
  bf16*  wkb   = (bf16*)take((size_t)KVD * DIM * 2);
  bf16*  wvb   = (bf16*)take((size_t)KVD * DIM * 2);
  bf16*  wob   = (bf16*)take((size_t)DIM * DIM * 2);
  bf16*  Qb    = (bf16*)take((size_t)SEQ * DIM * 2);
  bf16*  Kb    = (bf16*)take((size_t)SEQ * KVD * 2);
  bf16*  Vt    = (bf16*)take((size_t)NKV * HD * SEQ * 2);
  bf16*  attnb = (bf16*)take((size_t)SEQ * DIM * 2);

  // fused cast (1 launch, 12.6M float4)
  cast_all_kernel<<<C4 / 256, 256, 0, stream>>>(x, wq, wk, wv, wo,
                                                xb, wqb, wkb, wvb, wob);

  // fused QKV projection + RoPE/scale/V-transpose epilogue (bf16 outputs)
  qkv_gemm_kernel<<<dim3(48, 16), 256, 0, stream>>>(xb, wqb, wkb, wvb,
                                                    fc, fs, Qb, Kb, Vt);

  // flash attention (512 linear blocks, big/small qt pairing)
  attn_kernel<<<dim3(512), 256, 0, stream>>>(Qb, Kb, Vt, attnb);

  // output projection
  out_gemm_kernel<<<dim3(32, 16), 256, 0, stream>>>(attnb, wob, out);
}